// Round 11
// baseline (158.063 us; speedup 1.0000x reference)
//
#include <hip/hip_runtime.h>

#define BATCH 100000

typedef float v2 __attribute__((ext_vector_type(2)));

__device__ __forceinline__ v2 fma2(v2 a, v2 b, v2 c) { return __builtin_elementwise_fma(a, b, c); }
__device__ __forceinline__ v2 relu2(v2 a) { v2 z = {0.f, 0.f}; return __builtin_elementwise_max(a, z); }
__device__ __forceinline__ v2 splat(float a) { v2 r = {a, a}; return r; }
__device__ __forceinline__ v2 ldv2(const float* p) { return *(const v2*)p; }

// R19 = R18 (W2-in-LDS hybrid, best dispatch 50.3) wrapped in an
// exactly-co-resident persistent grid: 782 blocks (3.05/CU, all resident
// at once; cap is 4/CU), each looping over 2 sample-groups of 64.
// Theory: R8-R18 varied weight transport, samples/wave, waves/SIMD,
// FMA-per-load, barriers, code size -- wall stuck 50-56 us, VALU-busy
// ~22-27 us, idle ~46% INVARIANT to all of it. The only untouched axis
// is the dispatch envelope: 782-1563 short-lived blocks -> ramp + tail +
// refill gaps dilute occupancy (measured 28% vs >=50% steady-state).
// Persistent balanced grid pays the ramp once, has no refill churn, and
// iteration 2's weight s_loads hit warm K$/L2.
// Loop hazards: accL/rrL/eeL cross-iteration write-vs-read pairs are
// separated by >=2 intervening __syncthreads (verified per-array).
// unroll 1 on the group loop (spill discipline, R13 lesson).
// readfirstlane(h) kept (R9/R10). Tripwires: WRITE ~781 KB, VGPR <=84.
__global__ __launch_bounds__(256, 4) void barrier_net(
    const float* __restrict__ x,
    const float* __restrict__ phi_w1, const float* __restrict__ phi_b1,
    const float* __restrict__ phi_w2, const float* __restrict__ phi_b2,
    const float* __restrict__ obs_w1, const float* __restrict__ obs_b1,
    const float* __restrict__ obs_w2, const float* __restrict__ obs_b2,
    const float* __restrict__ rho_w1, const float* __restrict__ rho_b1,
    const float* __restrict__ rho_w2, const float* __restrict__ rho_b2,
    const float* __restrict__ psi_w1, const float* __restrict__ psi_b1,
    const float* __restrict__ psi_w2, const float* __restrict__ psi_b2,
    float2* __restrict__ out)
{
    __shared__ float W2L[2048];          // [0,1024) phi_w2, [1024,2048) obs_w2
    __shared__ float accL[2][2][32][16];
    __shared__ float rrL[2][2][32][2];
    __shared__ float eeL[2][2][32][2];

    // ---- cooperative W2 copy: ONCE per block (amortized over 2 groups) ----
    {
        const int i = threadIdx.x;
#pragma unroll
        for (int k = 0; k < 4; ++k) {
            W2L[i + 256 * k]        = phi_w2[i + 256 * k];
            W2L[1024 + i + 256 * k] = obs_w2[i + 256 * k];
        }
    }

    const int lane = threadIdx.x & 63;
    const int wave = threadIdx.x >> 6;
    const int pair = wave >> 1;
    const int h    = wave & 1;       // hidden half owned by this wave
    const int kk   = lane >> 1;      // sample index within the pair-group
    const int t    = lane & 1;       // lane half within the sample

    // ---- uniform hidden-slice base pointers (readfirstlane: R9/R10) ----
    const int HB = __builtin_amdgcn_readfirstlane(h) * 32;
    const int hu = HB >> 5;
    const float* pw1 = phi_w1 + HB;                 // row stride 64
    const float* pb1 = phi_b1 + HB;
    const float* pw2 = W2L + HB * 16;               // W2 row slice (LDS)
    const float* qw1 = obs_w1 + HB;
    const float* qb1 = obs_b1 + HB;
    const float* qw2 = W2L + 1024 + HB * 16;        // W2 row slice (LDS)
    const float* rw1 = rho_w1 + HB;                 // row stride 64
    const float* rb1 = rho_b1 + HB;
    const float* rw2 = rho_w2 + (size_t)HB * 2;
    const float* sw1 = psi_w1 + HB;
    const float* sb1 = psi_b1 + HB;
    const float* sw2 = psi_w2 + (size_t)HB * 2;

    __syncthreads();   // W2L staged

#pragma unroll 1
    for (int it = 0; it < 2; ++it) {
        const int gi = blockIdx.x * 2 + it;          // sample-group index
        int s = gi * 64 + pair * 32 + kk;
        const bool valid = (s < BATCH);
        if (!valid) s = BATCH - 1;   // clamp: in-bounds loads, stay for syncs
        const float* xr = x + (size_t)s * 85;

        // ---- per-lane slice: 8 neighbors ----
        float nb[8][4];
        const int nbase = 5 + 32 * t;
#pragma unroll
        for (int n = 0; n < 8; ++n)
#pragma unroll
            for (int k = 0; k < 4; ++k)
                nb[n][k] = xr[nbase + 4 * n + k];

        // ---- barrier partial: wave 0 only (it does the final store) ----
        float bar0 = 0.f, bar1 = 0.f;
        if (hu == 0) {
#pragma unroll
            for (int n = 0; n < 8; ++n) {
                float p0 = -nb[n][0], p1 = -nb[n][1];
                float r  = __builtin_amdgcn_sqrtf(fmaf(p0, p0, p1 * p1));
                float sc = 0.01f * __builtin_amdgcn_rcpf(r - 0.2f);
                bar0 = fmaf(sc, p0, bar0);
                bar1 = fmaf(sc, p1, bar1);
            }
            bar0 += __shfl_xor(bar0, 1);
            bar1 += __shfl_xor(bar1, 1);
        }

        // ---- acc partial: the 4 units carry 1/4 of the bias totals ----
        v2 acc[8];
#pragma unroll
        for (int p = 0; p < 8; ++p)
            acc[p] = fma2(splat(4.f), ldv2(phi_b2 + 2 * p),
                     fma2(splat(2.f), ldv2(obs_b2 + 2 * p), splat(0.f)));

        // ---- phi: 4 chunks of 8 hidden; W1 via s_load, W2 via LDS ----
#pragma unroll 2
        for (int c = 0; c < 4; ++c) {
            const int hb = 8 * c;
            v2 hsv[4] = {{0.f,0.f},{0.f,0.f},{0.f,0.f},{0.f,0.f}};
#pragma unroll
            for (int n = 0; n < 8; ++n) {
#pragma unroll
                for (int p = 0; p < 4; ++p) {
                    v2 tv = fma2(splat(nb[n][0]), ldv2(pw1 + hb + 2 * p),
                            fma2(splat(nb[n][1]), ldv2(pw1 + 64 + hb + 2 * p),
                            fma2(splat(nb[n][2]), ldv2(pw1 + 128 + hb + 2 * p),
                            fma2(splat(nb[n][3]), ldv2(pw1 + 192 + hb + 2 * p),
                                                  ldv2(pb1 + hb + 2 * p)))));
                    hsv[p] += relu2(tv);
                }
            }
#pragma unroll
            for (int p = 0; p < 4; ++p) {
                const float* r0 = pw2 + (hb + 2 * p) * 16;
                v2 hx = splat(hsv[p].x), hy = splat(hsv[p].y);
#pragma unroll
                for (int q = 0; q < 8; ++q)
                    acc[q] = fma2(hy, ldv2(r0 + 16 + 2 * q),
                             fma2(hx, ldv2(r0 + 2 * q), acc[q]));
            }
        }

        // ---- per-lane slice: 4 observations ----
        float ob[4][2];
        const int obase = 69 + 8 * t;
#pragma unroll
        for (int o = 0; o < 4; ++o) {
            ob[o][0] = xr[obase + 2 * o];
            ob[o][1] = xr[obase + 2 * o + 1];
        }

        // ---- obs: same chunking; W2 via LDS ----
#pragma unroll 2
        for (int c = 0; c < 4; ++c) {
            const int hb = 8 * c;
            v2 hsv[4] = {{0.f,0.f},{0.f,0.f},{0.f,0.f},{0.f,0.f}};
#pragma unroll
            for (int o = 0; o < 4; ++o) {
#pragma unroll
                for (int p = 0; p < 4; ++p) {
                    v2 tv = fma2(splat(ob[o][0]), ldv2(qw1 + hb + 2 * p),
                            fma2(splat(ob[o][1]), ldv2(qw1 + 64 + hb + 2 * p),
                                                  ldv2(qb1 + hb + 2 * p)));
                    hsv[p] += relu2(tv);
                }
            }
#pragma unroll
            for (int p = 0; p < 4; ++p) {
                const float* r0 = qw2 + (hb + 2 * p) * 16;
                v2 hx = splat(hsv[p].x), hy = splat(hsv[p].y);
#pragma unroll
                for (int q = 0; q < 8; ++q)
                    acc[q] = fma2(hy, ldv2(r0 + 16 + 2 * q),
                             fma2(hx, ldv2(r0 + 2 * q), acc[q]));
            }
        }

        // ---- combine across the lane pair (t) ----
#pragma unroll
        for (int p = 0; p < 8; ++p) {
            acc[p].x += __shfl_xor(acc[p].x, 1);
            acc[p].y += __shfl_xor(acc[p].y, 1);
        }

        // ---- combine across the wave pair (h); static acc idx only ----
        {
            float* slot = &accL[pair][h][kk][8 * t];
#pragma unroll
            for (int p = 0; p < 4; ++p) {
                v2 lo = acc[p], hi = acc[p + 4];
                v2 sel;
                sel.x = t ? hi.x : lo.x;
                sel.y = t ? hi.y : lo.y;
                *(v2*)(slot + 2 * p) = sel;
            }
        }
        __syncthreads();
        {
            const float* oslot = &accL[pair][h ^ 1][kk][0];
#pragma unroll
            for (int p = 0; p < 8; ++p)
                acc[p] += ldv2(oslot + 2 * p);
        }
        __syncthreads();   // guard: accL reads done before next writes

        const float g0 = xr[0], g1 = xr[1];

        // ---- rho: 16 -> hidden slice -> 2 (partial); s_load weights ----
        v2 rr = (hu == 0) ? ldv2(rho_b2) : splat(0.f);
#pragma unroll 2
        for (int c = 0; c < 4; ++c) {
            const int hb = 8 * c;
            v2 tt[4];
#pragma unroll
            for (int p = 0; p < 4; ++p)
                tt[p] = ldv2(rb1 + hb + 2 * p);
#pragma unroll
            for (int j = 0; j < 8; ++j) {
                v2 ax = splat(acc[j].x), ay = splat(acc[j].y);
                const float* rj0 = rw1 + (size_t)(2 * j) * 64 + hb;
                const float* rj1 = rw1 + (size_t)(2 * j + 1) * 64 + hb;
#pragma unroll
                for (int p = 0; p < 4; ++p)
                    tt[p] = fma2(ay, ldv2(rj1 + 2 * p),
                            fma2(ax, ldv2(rj0 + 2 * p), tt[p]));
            }
#pragma unroll
            for (int p = 0; p < 4; ++p) {
                v2 u = relu2(tt[p]);
                rr = fma2(splat(u.x), ldv2(rw2 + 2 * (hb + 2 * p)), rr);
                rr = fma2(splat(u.y), ldv2(rw2 + 2 * (hb + 2 * p) + 2), rr);
            }
        }
        rrL[pair][h][kk][t] = t ? rr.y : rr.x;   // both lanes hold same rr
        __syncthreads();
        {
            v2 rro = ldv2(&rrL[pair][h ^ 1][kk][0]);
            rr += rro;                            // full rho output
        }

        // ---- psi: [r0, r1, g0, g1] -> hidden slice -> 2 (partial) ----
        v2 ee = (hu == 0) ? ldv2(psi_b2) : splat(0.f);
#pragma unroll 2
        for (int c = 0; c < 4; ++c) {
            const int hb = 8 * c;
#pragma unroll
            for (int p = 0; p < 4; ++p) {
                v2 tv = fma2(splat(rr.x), ldv2(sw1 + hb + 2 * p),
                        fma2(splat(rr.y), ldv2(sw1 + 64 + hb + 2 * p),
                        fma2(splat(g0),   ldv2(sw1 + 128 + hb + 2 * p),
                        fma2(splat(g1),   ldv2(sw1 + 192 + hb + 2 * p),
                                          ldv2(sb1 + hb + 2 * p)))));
                v2 u = relu2(tv);
                ee = fma2(splat(u.x), ldv2(sw2 + 2 * (hb + 2 * p)), ee);
                ee = fma2(splat(u.y), ldv2(sw2 + 2 * (hb + 2 * p) + 2), ee);
            }
        }
        eeL[pair][h][kk][t] = t ? ee.y : ee.x;
        __syncthreads();

        if (hu == 0 && t == 0 && valid) {
            v2 eeo = ldv2(&eeL[pair][1][kk][0]);
            float a0 = tanhf(tanhf(ee.x + eeo.x) + bar0);
            float a1 = tanhf(tanhf(ee.y + eeo.y) + bar1);
            out[s] = make_float2(2.f * a0, 2.f * a1);
        }
    }
}

extern "C" void kernel_launch(void* const* d_in, const int* in_sizes, int n_in,
                              void* d_out, int out_size, void* d_ws, size_t ws_size,
                              hipStream_t stream) {
    // 782 blocks x 2 groups of 64 samples = 100,096 >= BATCH; 3.05 blocks/CU
    // -> the whole grid is co-resident (cap 4/CU), balanced 2 groups/block.
    dim3 grid(782), block(256);
    barrier_net<<<grid, block, 0, stream>>>(
        (const float*)d_in[0],
        (const float*)d_in[1],  (const float*)d_in[2],  (const float*)d_in[3],  (const float*)d_in[4],
        (const float*)d_in[5],  (const float*)d_in[6],  (const float*)d_in[7],  (const float*)d_in[8],
        (const float*)d_in[9],  (const float*)d_in[10], (const float*)d_in[11], (const float*)d_in[12],
        (const float*)d_in[13], (const float*)d_in[14], (const float*)d_in[15], (const float*)d_in[16],
        (float2*)d_out);
}